// Round 3
// baseline (163.820 us; speedup 1.0000x reference)
//
#include <hip/hip_runtime.h>
#include <cstdint>

#define B_SZ   16384
#define H_SZ   512
#define DIN    256
#define TEMB   16
#define KP     1344          // packed K: x[0,256) h[256,768) c[768,1280) delt[1280,1296) pad[1296,1344)
#define KPB    2688          // KP*2 bytes per row
#define NHT    41            // 41 half-K-tiles of 32 (skip zero pad [1312,1344))
#define BH     8388608L      // B_SZ*H_SZ
#define SLOT   28672         // LDS slot: A 16 KB (256 rows x 64 B) + W 12 KB (6 gates x 32 cols x 64 B)

typedef __attribute__((ext_vector_type(4))) float f32x4;
typedef __bf16 bf16x8 __attribute__((ext_vector_type(8)));

typedef const __attribute__((address_space(1))) unsigned int gu32_t;
typedef __attribute__((address_space(3)))       unsigned int lu32_t;

__device__ __forceinline__ void gld16(const void* g, void* l) {
  __builtin_amdgcn_global_load_lds((gu32_t*)(uintptr_t)g,
                                   (lu32_t*)(unsigned int)(uintptr_t)l, 16, 0, 0);
}

__device__ __forceinline__ unsigned short f2bf(float f) {
  unsigned int u = __float_as_uint(f);
  u += 0x7FFFu + ((u >> 16) & 1u);   // RNE; inputs finite
  return (unsigned short)(u >> 16);
}

__device__ __forceinline__ float sigm(float v)  { return 1.0f / (1.0f + __expf(-v)); }
__device__ __forceinline__ float tanhx(float v) { return 2.0f / (1.0f + __expf(-2.0f * v)) - 1.0f; }

// ---------------- prep: pack A = [x|h|c|delt|0] as bf16 [B][KP] ----------------
__global__ void prep_a_kernel(const float* __restrict__ x, const float* __restrict__ h,
                              const float* __restrict__ c, const float* __restrict__ dl,
                              unsigned short* __restrict__ Ap) {
  long idx = (long)blockIdx.x * 256 + threadIdx.x;
  const long n4 = (long)B_SZ * KP / 4;
  if (idx >= n4) return;
  int row = (int)(idx / (KP / 4));
  int k4  = (int)(idx % (KP / 4)) * 4;
  float4 v = make_float4(0.f, 0.f, 0.f, 0.f);
  if (k4 < 256)       v = *(const float4*)(x  + (long)row * DIN  + k4);
  else if (k4 < 768)  v = *(const float4*)(h  + (long)row * H_SZ + (k4 - 256));
  else if (k4 < 1280) v = *(const float4*)(c  + (long)row * H_SZ + (k4 - 768));
  else if (k4 < 1296) v = *(const float4*)(dl + (long)row * TEMB + (k4 - 1280));
  ushort4 o;
  o.x = f2bf(v.x); o.y = f2bf(v.y); o.z = f2bf(v.z); o.w = f2bf(v.w);
  *(ushort4*)(Ap + idx * 4) = o;
}

// ---------------- prep: pack Wp[6][512][KP] bf16 ----------------
__global__ void prep_w_kernel(const float* __restrict__ Wix, const float* __restrict__ Wih, const float* __restrict__ Wic,
                              const float* __restrict__ Wfx, const float* __restrict__ Wfh, const float* __restrict__ Wfc,
                              const float* __restrict__ Wtx, const float* __restrict__ Wtt,
                              const float* __restrict__ Wcx, const float* __restrict__ Wch,
                              const float* __restrict__ Wox, const float* __restrict__ Woh,
                              const float* __restrict__ Woc, const float* __restrict__ Wot,
                              unsigned short* __restrict__ Wp) {
  long idx = (long)blockIdx.x * 256 + threadIdx.x;
  const long n4 = 6L * H_SZ * KP / 4;
  if (idx >= n4) return;
  int k4   = (int)(idx % (KP / 4)) * 4;
  int rest = (int)(idx / (KP / 4));
  int n = rest & 511;
  int g = rest >> 9;
  const float* src = nullptr; long o = 0;
  if (g == 0) {
    if (k4 < 256)       { src = Wix; o = (long)n * 256 + k4; }
    else if (k4 < 768)  { src = Wih; o = (long)n * 512 + (k4 - 256); }
    else if (k4 < 1280) { src = Wic; o = (long)n * 512 + (k4 - 768); }
  } else if (g == 1) {
    if (k4 < 256)       { src = Wfx; o = (long)n * 256 + k4; }
    else if (k4 < 768)  { src = Wfh; o = (long)n * 512 + (k4 - 256); }
    else if (k4 < 1280) { src = Wfc; o = (long)n * 512 + (k4 - 768); }
  } else if (g == 2) {
    if (k4 < 256)       { src = Wtx; o = (long)n * 256 + k4; }
  } else if (g == 3) {
    if (k4 < 256)       { src = Wcx; o = (long)n * 256 + k4; }
    else if (k4 < 768)  { src = Wch; o = (long)n * 512 + (k4 - 256); }
  } else if (g == 4) {
    if (k4 < 256)       { src = Wox; o = (long)n * 256 + k4; }
    else if (k4 < 768)  { src = Woh; o = (long)n * 512 + (k4 - 256); }
    else if (k4 < 1280) { src = Woc; o = (long)n * 512 + (k4 - 768); }
    else if (k4 < 1296) { src = Wot; o = (long)n * 16 + (k4 - 1280); }
  } else {
    if (k4 >= 1280 && k4 < 1296) { src = Wtt; o = (long)n * 16 + (k4 - 1280); }
  }
  float4 v = make_float4(0.f, 0.f, 0.f, 0.f);
  if (src) v = *(const float4*)(src + o);
  ushort4 u;
  u.x = f2bf(v.x); u.y = f2bf(v.y); u.z = f2bf(v.z); u.w = f2bf(v.w);
  *(ushort4*)(Wp + idx * 4) = u;
}

// LDS semantic layout per slot:
//   A:  addr = row*64 + ((kgrp + (row>>1))&3)*16          row in [0,256)
//   W:  addr = 16384 + gate*2048 + col*64 + ((kgrp+(col>>1))&3)*16
// gld16 writes 1KB chunks linearly; the source granule per lane is pre-permuted
// so the stored layout matches the above (rule: linear dest + inverse-perm source).

// stage half-tile ht into slot `slot`
__device__ __forceinline__ void stage_ht(char* lds, int slot, int ht,
                                         const char* sA0, const char* sA1,
                                         const char* sW0, const char* sW1,
                                         int wid) {
  const int sb = slot * SLOT;
  const unsigned kb = (unsigned)ht * 64u;
  gld16(sA0 + kb, lds + sb + wid * 2048);
  gld16(sA1 + kb, lds + sb + wid * 2048 + 1024);
  if (wid < 4) {   // waves 0-3: both col-halves of gates 0-3
    gld16(sW0 + kb, lds + sb + 16384 + wid * 2048);
    gld16(sW1 + kb, lds + sb + 16384 + wid * 2048 + 1024);
  } else {         // waves 4-7: one col-half of gates 4-5
    gld16(sW0 + kb, lds + sb + 16384 + (wid + 4) * 1024);
  }
}

template<unsigned MASK, int NW4, int NW3, bool STAGE>
__device__ __forceinline__ void phase_ht(char* lds, int h,
    const char* sA0, const char* sA1, const char* sW0, const char* sW1,
    int wid, int aro, int bro, f32x4 acc[6][4]) {
  if (STAGE) stage_ht(lds, (h + 3) & 3, h + 3, sA0, sA1, sW0, sW1, wid);
  if (wid < 4) asm volatile("s_waitcnt vmcnt(%0)" :: "i"(NW4) : "memory");
  else         asm volatile("s_waitcnt vmcnt(%0)" :: "i"(NW3) : "memory");
  __builtin_amdgcn_s_barrier();          // all waves' half-tile-h data landed
  __builtin_amdgcn_sched_barrier(0);     // pin ds_reads below the barrier
  const char* base = lds + (h & 3) * SLOT;
  bf16x8 a0 = *(const bf16x8*)(base + aro);
  bf16x8 a1 = *(const bf16x8*)(base + aro + 1024);
  bf16x8 a2 = *(const bf16x8*)(base + aro + 2048);
  bf16x8 a3 = *(const bf16x8*)(base + aro + 3072);
  __builtin_amdgcn_s_setprio(1);
#pragma unroll
  for (int g = 0; g < 6; ++g) {
    if (MASK & (1u << g)) {
      bf16x8 b = *(const bf16x8*)(base + bro + g * 2048);
      acc[g][0] = __builtin_amdgcn_mfma_f32_16x16x32_bf16(a0, b, acc[g][0], 0, 0, 0);
      acc[g][1] = __builtin_amdgcn_mfma_f32_16x16x32_bf16(a1, b, acc[g][1], 0, 0, 0);
      acc[g][2] = __builtin_amdgcn_mfma_f32_16x16x32_bf16(a2, b, acc[g][2], 0, 0, 0);
      acc[g][3] = __builtin_amdgcn_mfma_f32_16x16x32_bf16(a3, b, acc[g][3], 0, 0, 0);
    }
  }
  __builtin_amdgcn_s_setprio(0);
  __builtin_amdgcn_s_barrier();          // all waves done reading slot h -> reusable
}

// ---------------- main fused kernel ----------------
__global__ __launch_bounds__(512, 2) void lstm_main(
    const unsigned short* __restrict__ Ap, const unsigned short* __restrict__ Wp,
    const float* __restrict__ c_prev,
    const float* __restrict__ b_ix, const float* __restrict__ b_fx,
    const float* __restrict__ b_tx, const float* __restrict__ b_cx,
    const float* __restrict__ b_ox,
    float* __restrict__ out)
{
  __shared__ __align__(16) char lds[4 * SLOT];   // 114688 B, 1 wg/CU

  const int tid  = threadIdx.x;
  const int lane = tid & 63;
  const int wid  = tid >> 6;

  // XCD swizzle: xcd owns col-blocks {2k,2k+1}; adjacent wg pair shares rb (A L2 reuse)
  const int bid = blockIdx.x;
  const int xcd = bid & 7;
  const int idx = bid >> 3;                  // 0..127
  const int rb  = idx >> 1;                  // 0..63
  const int cb  = (xcd << 1) | (idx & 1);    // 0..15
  const unsigned brow = (unsigned)rb * 256u;
  const int bcol = cb * 32;

  const int wr   = (wid >> 1) * 64;          // wave rows [wr, wr+64)
  const int wc16 = (wid & 1) * 16;           // wave cols [wc16, wc16+16)
  const int lrow = lane & 15;
  const int kgrp = lane >> 4;

  f32x4 acc[6][4];
  {
    f32x4 z = {0.f, 0.f, 0.f, 0.f};
#pragma unroll
    for (int g = 0; g < 6; ++g)
#pragma unroll
      for (int i = 0; i < 4; ++i) acc[g][i] = z;
  }

  // read offsets (swizzled slot within 64-B row)
  const int sread = ((kgrp + (lrow >> 1)) & 3) << 4;
  const int aro = (wr + lrow) * 64 + sread;
  const int bro = 16384 + (wc16 + lrow) * 64 + sread;

  // stage source pointers (per-lane pre-permuted granule)
  const int l4 = lane >> 2;
  const int kslot = (((lane & 3) - ((lane >> 3) & 3)) & 3) << 4;
  const char* apc = (const char*)Ap;
  const char* wpc = (const char*)Wp;
  const char* sA0 = apc + (size_t)(brow + wid * 32 +      l4) * KPB + kslot;
  const char* sA1 = apc + (size_t)(brow + wid * 32 + 16 + l4) * KPB + kslot;
  const char *sW0, *sW1;
  if (wid < 4) {
    sW0 = wpc + (size_t)(wid * 512 + bcol +      l4) * KPB + kslot;
    sW1 = wpc + (size_t)(wid * 512 + bcol + 16 + l4) * KPB + kslot;
  } else {
    const int gate = (wid >> 1) + 2, halfc = wid & 1;
    sW0 = wpc + (size_t)(gate * 512 + bcol + halfc * 16 + l4) * KPB + kslot;
    sW1 = sW0;
  }

  // prologue: 3 half-tiles in flight
  stage_ht(lds, 0, 0, sA0, sA1, sW0, sW1, wid);
  stage_ht(lds, 1, 1, sA0, sA1, sW0, sW1, wid);
  stage_ht(lds, 2, 2, sA0, sA1, sW0, sW1, wid);

#pragma unroll 1
  for (int h = 0; h < 8; ++h)
    phase_ht<0x1F, 12, 9, true>(lds, h, sA0, sA1, sW0, sW1, wid, aro, bro, acc);
#pragma unroll 1
  for (int h = 8; h < 24; ++h)
    phase_ht<0x1B, 12, 9, true>(lds, h, sA0, sA1, sW0, sW1, wid, aro, bro, acc);
#pragma unroll 1
  for (int h = 24; h < 38; ++h)
    phase_ht<0x13, 12, 9, true>(lds, h, sA0, sA1, sW0, sW1, wid, aro, bro, acc);
  phase_ht<0x13, 8, 6, false>(lds, 38, sA0, sA1, sW0, sW1, wid, aro, bro, acc);
  phase_ht<0x13, 4, 3, false>(lds, 39, sA0, sA1, sW0, sW1, wid, aro, bro, acc);
  phase_ht<0x30, 0, 0, false>(lds, 40, sA0, sA1, sW0, sW1, wid, aro, bro, acc);

  // ---------------- fused epilogue ----------------
  const int n = bcol + wc16 + lrow;
  const float bi  = b_ix[n], bff = b_fx[n], bt = b_tx[n], bc = b_cx[n], bo = b_ox[n];
  const int rbase = kgrp * 4;
#pragma unroll
  for (int i = 0; i < 4; ++i) {
#pragma unroll
    for (int r = 0; r < 4; ++r) {
      const long m   = (long)brow + wr + 16 * i + rbase + r;
      const long off = m * H_SZ + n;
      const float iv = sigm(acc[0][i][r] + bi);
      const float fv = sigm(acc[1][i][r] + bff);
      const float Tv = sigm(acc[2][i][r] + bt + sigm(acc[5][i][r]));
      const float kv = tanhx(acc[3][i][r] + bc);
      const float ov = sigm(acc[4][i][r] + bo);
      const float cp = c_prev[off];
      const float cn = iv * Tv * kv + fv * cp;
      out[off]          = ov * tanhx(cn);
      out[BH + off]     = cn;
      out[2 * BH + off] = Tv;
    }
  }
}

extern "C" void kernel_launch(void* const* d_in, const int* in_sizes, int n_in,
                              void* d_out, int out_size, void* d_ws, size_t ws_size,
                              hipStream_t stream) {
  const float* x      = (const float*)d_in[0];
  const float* h      = (const float*)d_in[1];
  const float* c_prev = (const float*)d_in[2];
  const float* dl     = (const float*)d_in[3];
  const float* W_ix = (const float*)d_in[4];
  const float* b_ix = (const float*)d_in[5];
  const float* W_ih = (const float*)d_in[6];
  const float* W_ic = (const float*)d_in[7];
  const float* W_fx = (const float*)d_in[8];
  const float* b_fx = (const float*)d_in[9];
  const float* W_fh = (const float*)d_in[10];
  const float* W_fc = (const float*)d_in[11];
  const float* W_tx = (const float*)d_in[12];
  const float* b_tx = (const float*)d_in[13];
  const float* W_tt = (const float*)d_in[14];
  const float* W_cx = (const float*)d_in[15];
  const float* b_cx = (const float*)d_in[16];
  const float* W_ch = (const float*)d_in[17];
  const float* W_ox = (const float*)d_in[18];
  const float* b_ox = (const float*)d_in[19];
  const float* W_oh = (const float*)d_in[20];
  const float* W_oc = (const float*)d_in[21];
  const float* W_ot = (const float*)d_in[22];

  unsigned short* Ap = (unsigned short*)d_ws;                                   // 44.04 MB
  unsigned short* Wp = (unsigned short*)((char*)d_ws + (size_t)B_SZ * KP * 2);  // +8.26 MB

  const long na4 = (long)B_SZ * KP / 4;
  prep_a_kernel<<<(int)((na4 + 255) / 256), 256, 0, stream>>>(x, h, c_prev, dl, Ap);
  const long nw4 = 6L * H_SZ * KP / 4;
  prep_w_kernel<<<(int)((nw4 + 255) / 256), 256, 0, stream>>>(
      W_ix, W_ih, W_ic, W_fx, W_fh, W_fc, W_tx, W_tt, W_cx, W_ch,
      W_ox, W_oh, W_oc, W_ot, Wp);

  lstm_main<<<1024, 512, 0, stream>>>(Ap, Wp, c_prev, b_ix, b_fx, b_tx, b_cx, b_ox,
                                      (float*)d_out);
}

// Round 4
// 138.646 us; speedup vs baseline: 1.1816x; 1.1816x over previous
//
#include <hip/hip_runtime.h>
#include <cstdint>

#define B_SZ   16384
#define H_SZ   512
#define DIN    256
#define TEMB   16
#define KP     1344          // packed K: x[0,256) h[256,768) c[768,1280) delt[1280,1296) pad[1296,1344)
#define KPB    2688          // KP*2 bytes per row
#define BH     8388608L      // B_SZ*H_SZ
#define SLOT   57344         // LDS slot: A 8 KB (128 rows x 64 B) + W 48 KB (6 g x 128 cols x 64 B)
#define GSTR   1376256       // 512*KPB: gate stride in Wp bytes

typedef __attribute__((ext_vector_type(4))) float f32x4;
typedef __bf16 bf16x8 __attribute__((ext_vector_type(8)));

typedef const __attribute__((address_space(1))) unsigned int gu32_t;
typedef __attribute__((address_space(3)))       unsigned int lu32_t;

__device__ __forceinline__ void gld16(const void* g, void* l) {
  __builtin_amdgcn_global_load_lds((gu32_t*)(uintptr_t)g,
                                   (lu32_t*)(unsigned int)(uintptr_t)l, 16, 0, 0);
}

__device__ __forceinline__ unsigned short f2bf(float f) {
  unsigned int u = __float_as_uint(f);
  u += 0x7FFFu + ((u >> 16) & 1u);   // RNE; inputs finite
  return (unsigned short)(u >> 16);
}

__device__ __forceinline__ float sigm(float v)  { return 1.0f / (1.0f + __expf(-v)); }
__device__ __forceinline__ float tanhx(float v) { return 2.0f / (1.0f + __expf(-2.0f * v)) - 1.0f; }

// ---------------- prep: pack A = [x|h|c|delt|0] as bf16 [B][KP] ----------------
__global__ void prep_a_kernel(const float* __restrict__ x, const float* __restrict__ h,
                              const float* __restrict__ c, const float* __restrict__ dl,
                              unsigned short* __restrict__ Ap) {
  long idx = (long)blockIdx.x * 256 + threadIdx.x;
  const long n4 = (long)B_SZ * KP / 4;
  if (idx >= n4) return;
  int row = (int)(idx / (KP / 4));
  int k4  = (int)(idx % (KP / 4)) * 4;
  float4 v = make_float4(0.f, 0.f, 0.f, 0.f);
  if (k4 < 256)       v = *(const float4*)(x  + (long)row * DIN  + k4);
  else if (k4 < 768)  v = *(const float4*)(h  + (long)row * H_SZ + (k4 - 256));
  else if (k4 < 1280) v = *(const float4*)(c  + (long)row * H_SZ + (k4 - 768));
  else if (k4 < 1296) v = *(const float4*)(dl + (long)row * TEMB + (k4 - 1280));
  ushort4 o;
  o.x = f2bf(v.x); o.y = f2bf(v.y); o.z = f2bf(v.z); o.w = f2bf(v.w);
  *(ushort4*)(Ap + idx * 4) = o;
}

// ---------------- prep: pack Wp[6][512][KP] bf16 ----------------
__global__ void prep_w_kernel(const float* __restrict__ Wix, const float* __restrict__ Wih, const float* __restrict__ Wic,
                              const float* __restrict__ Wfx, const float* __restrict__ Wfh, const float* __restrict__ Wfc,
                              const float* __restrict__ Wtx, const float* __restrict__ Wtt,
                              const float* __restrict__ Wcx, const float* __restrict__ Wch,
                              const float* __restrict__ Wox, const float* __restrict__ Woh,
                              const float* __restrict__ Woc, const float* __restrict__ Wot,
                              unsigned short* __restrict__ Wp) {
  long idx = (long)blockIdx.x * 256 + threadIdx.x;
  const long n4 = 6L * H_SZ * KP / 4;
  if (idx >= n4) return;
  int k4   = (int)(idx % (KP / 4)) * 4;
  int rest = (int)(idx / (KP / 4));
  int n = rest & 511;
  int g = rest >> 9;
  const float* src = nullptr; long o = 0;
  if (g == 0) {
    if (k4 < 256)       { src = Wix; o = (long)n * 256 + k4; }
    else if (k4 < 768)  { src = Wih; o = (long)n * 512 + (k4 - 256); }
    else if (k4 < 1280) { src = Wic; o = (long)n * 512 + (k4 - 768); }
  } else if (g == 1) {
    if (k4 < 256)       { src = Wfx; o = (long)n * 256 + k4; }
    else if (k4 < 768)  { src = Wfh; o = (long)n * 512 + (k4 - 256); }
    else if (k4 < 1280) { src = Wfc; o = (long)n * 512 + (k4 - 768); }
  } else if (g == 2) {
    if (k4 < 256)       { src = Wtx; o = (long)n * 256 + k4; }
  } else if (g == 3) {
    if (k4 < 256)       { src = Wcx; o = (long)n * 256 + k4; }
    else if (k4 < 768)  { src = Wch; o = (long)n * 512 + (k4 - 256); }
  } else if (g == 4) {
    if (k4 < 256)       { src = Wox; o = (long)n * 256 + k4; }
    else if (k4 < 768)  { src = Woh; o = (long)n * 512 + (k4 - 256); }
    else if (k4 < 1280) { src = Woc; o = (long)n * 512 + (k4 - 768); }
    else if (k4 < 1296) { src = Wot; o = (long)n * 16 + (k4 - 1280); }
  } else {
    if (k4 >= 1280 && k4 < 1296) { src = Wtt; o = (long)n * 16 + (k4 - 1280); }
  }
  float4 v = make_float4(0.f, 0.f, 0.f, 0.f);
  if (src) v = *(const float4*)(src + o);
  ushort4 u;
  u.x = f2bf(v.x); u.y = f2bf(v.y); u.z = f2bf(v.z); u.w = f2bf(v.w);
  *(ushort4*)(Wp + idx * 4) = u;
}

// LDS semantic layout per slot (K-phase = 32 elems = 64 B per row):
//   A: byte = row*64 + ((kgrp + (row>>1))&3)*16,        row in [0,128)
//   W: byte = 8192 + g*8192 + col*64 + ((kgrp+(col>>1))&3)*16
// gld16 writes 1KB chunks (16 rows) linearly; per-lane source granule is
// pre-permuted (kslot) so the stored layout matches (linear dest rule).

// stage half-tile ht (K [ht*32, ht*32+32)) into LDS slot at byte `sb`
template<unsigned SMASK>
__device__ __forceinline__ void stage_ht(char* lds, int sb, int ht,
                                         const char* sA, const char* sW, int wid) {
  const unsigned kb = (unsigned)ht * 64u;
  gld16(sA + kb, lds + sb + wid * 1024);
#pragma unroll
  for (int g = 0; g < 6; ++g)
    if (SMASK & (1u << g))
      gld16(sW + (unsigned)g * GSTR + kb, lds + sb + 8192 + g * 8192 + wid * 1024);
}

template<unsigned CM, unsigned SM, int NW, bool ST>
__device__ __forceinline__ void phase_ht(char* lds, int h,
    const char* sA, const char* sW, int wid,
    int aro, int wro, f32x4 acc[6][4][2]) {
  if (ST) stage_ht<SM>(lds, ((h + 1) & 1) * SLOT, h + 1, sA, sW, wid);
  asm volatile("s_waitcnt vmcnt(%0)" :: "i"(NW) : "memory");
  __builtin_amdgcn_s_barrier();          // all waves' half-tile-h data landed
  __builtin_amdgcn_sched_barrier(0);     // pin ds_reads below the barrier
  const char* base = lds + (h & 1) * SLOT;
  bf16x8 a0 = *(const bf16x8*)(base + aro);
  bf16x8 a1 = *(const bf16x8*)(base + aro + 1024);
  bf16x8 a2 = *(const bf16x8*)(base + aro + 2048);
  bf16x8 a3 = *(const bf16x8*)(base + aro + 3072);
  __builtin_amdgcn_s_setprio(1);
#pragma unroll
  for (int g = 0; g < 6; ++g) {
    if (CM & (1u << g)) {
      const char* wb = base + 8192 + g * 8192 + wro;
      bf16x8 b0 = *(const bf16x8*)(wb);
      bf16x8 b1 = *(const bf16x8*)(wb + 1024);
      acc[g][0][0] = __builtin_amdgcn_mfma_f32_16x16x32_bf16(a0, b0, acc[g][0][0], 0, 0, 0);
      acc[g][1][0] = __builtin_amdgcn_mfma_f32_16x16x32_bf16(a1, b0, acc[g][1][0], 0, 0, 0);
      acc[g][2][0] = __builtin_amdgcn_mfma_f32_16x16x32_bf16(a2, b0, acc[g][2][0], 0, 0, 0);
      acc[g][3][0] = __builtin_amdgcn_mfma_f32_16x16x32_bf16(a3, b0, acc[g][3][0], 0, 0, 0);
      acc[g][0][1] = __builtin_amdgcn_mfma_f32_16x16x32_bf16(a0, b1, acc[g][0][1], 0, 0, 0);
      acc[g][1][1] = __builtin_amdgcn_mfma_f32_16x16x32_bf16(a1, b1, acc[g][1][1], 0, 0, 0);
      acc[g][2][1] = __builtin_amdgcn_mfma_f32_16x16x32_bf16(a2, b1, acc[g][2][1], 0, 0, 0);
      acc[g][3][1] = __builtin_amdgcn_mfma_f32_16x16x32_bf16(a3, b1, acc[g][3][1], 0, 0, 0);
    }
  }
  __builtin_amdgcn_s_setprio(0);
  __builtin_amdgcn_s_barrier();          // all waves done reading slot h -> reusable
}

// ---------------- main fused kernel ----------------
__global__ __launch_bounds__(512, 2) void lstm_main(
    const unsigned short* __restrict__ Ap, const unsigned short* __restrict__ Wp,
    const float* __restrict__ c_prev,
    const float* __restrict__ b_ix, const float* __restrict__ b_fx,
    const float* __restrict__ b_tx, const float* __restrict__ b_cx,
    const float* __restrict__ b_ox,
    float* __restrict__ out)
{
  __shared__ __align__(16) char lds[2 * SLOT];   // 114688 B, 1 wg/CU

  const int tid  = threadIdx.x;
  const int lane = tid & 63;
  const int wid  = tid >> 6;

  // XCD swizzle: XCD pair {2c,2c+1} owns col-block c (W slice ~2MB, L2-resident);
  // bijective: 512 wgs = 128 rb x 4 cb
  const int bid = blockIdx.x;
  const int xcd = bid & 7;
  const int idx = bid >> 3;                  // 0..63
  const int cb  = xcd >> 1;                  // 0..3
  const int rb  = (idx << 1) | (xcd & 1);    // 0..127
  const unsigned brow = (unsigned)rb * 128u;
  const int bcol = cb * 128;

  const int wr  = (wid >> 2) * 64;           // wave rows [wr, wr+64)
  const int wcg = (wid & 3) * 32;            // wave cols [wcg, wcg+32)
  const int lrow = lane & 15;
  const int kgrp = lane >> 4;

  f32x4 acc[6][4][2];
  {
    f32x4 z = {0.f, 0.f, 0.f, 0.f};
#pragma unroll
    for (int g = 0; g < 6; ++g)
#pragma unroll
      for (int i = 0; i < 4; ++i) { acc[g][i][0] = z; acc[g][i][1] = z; }
  }

  // swizzled read offsets
  const int sread = ((kgrp + (lrow >> 1)) & 3) << 4;
  const int aro = (wr + lrow) * 64 + sread;
  const int wro = (wcg + lrow) * 64 + sread;

  // stage source pointers (per-lane pre-permuted granule)
  const int l4 = lane >> 2;
  const int kslot = (((lane & 3) - ((lane >> 3) & 3)) & 3) << 4;
  const char* sA = (const char*)Ap + (size_t)(brow + wid * 16 + l4) * KPB + kslot;
  const char* sW = (const char*)Wp + (size_t)(bcol + wid * 16 + l4) * KPB + kslot;

  // prologue: half-tile 0 in flight
  stage_ht<0x1F>(lds, 0, 0, sA, sW, wid);

#pragma unroll 1
  for (int h = 0; h < 7; ++h)
    phase_ht<0x1F, 0x1F, 6, true>(lds, h, sA, sW, wid, aro, wro, acc);
  phase_ht<0x1F, 0x1B, 5, true>(lds, 7, sA, sW, wid, aro, wro, acc);
#pragma unroll 1
  for (int h = 8; h < 23; ++h)
    phase_ht<0x1B, 0x1B, 5, true>(lds, h, sA, sW, wid, aro, wro, acc);
  phase_ht<0x1B, 0x13, 4, true>(lds, 23, sA, sW, wid, aro, wro, acc);
#pragma unroll 1
  for (int h = 24; h < 39; ++h)
    phase_ht<0x13, 0x13, 4, true>(lds, h, sA, sW, wid, aro, wro, acc);
  phase_ht<0x13, 0x30, 3, true>(lds, 39, sA, sW, wid, aro, wro, acc);
  phase_ht<0x30, 0x00, 0, false>(lds, 40, sA, sW, wid, aro, wro, acc);

  // ---------------- fused epilogue ----------------
  const int n0 = bcol + wcg + lrow;
  const int rbase = kgrp * 4;
#pragma unroll
  for (int cf = 0; cf < 2; ++cf) {
    const int n = n0 + 16 * cf;
    const float bi  = b_ix[n], bff = b_fx[n], bt = b_tx[n], bc = b_cx[n], bo = b_ox[n];
#pragma unroll
    for (int i = 0; i < 4; ++i) {
#pragma unroll
      for (int r = 0; r < 4; ++r) {
        const long m   = (long)brow + wr + 16 * i + rbase + r;
        const long off = m * H_SZ + n;
        const float iv = sigm(acc[0][i][cf][r] + bi);
        const float fv = sigm(acc[1][i][cf][r] + bff);
        const float Tv = sigm(acc[2][i][cf][r] + bt + sigm(acc[5][i][cf][r]));
        const float kv = tanhx(acc[3][i][cf][r] + bc);
        const float ov = sigm(acc[4][i][cf][r] + bo);
        const float cp = c_prev[off];
        const float cn = iv * Tv * kv + fv * cp;
        out[off]          = ov * tanhx(cn);
        out[BH + off]     = cn;
        out[2 * BH + off] = Tv;
      }
    }
  }
}

extern "C" void kernel_launch(void* const* d_in, const int* in_sizes, int n_in,
                              void* d_out, int out_size, void* d_ws, size_t ws_size,
                              hipStream_t stream) {
  const float* x      = (const float*)d_in[0];
  const float* h      = (const float*)d_in[1];
  const float* c_prev = (const float*)d_in[2];
  const float* dl     = (const float*)d_in[3];
  const float* W_ix = (const float*)d_in[4];
  const float* b_ix = (const float*)d_in[5];
  const float* W_ih = (const float*)d_in[6];
  const float* W_ic = (const float*)d_in[7];
  const float* W_fx = (const float*)d_in[8];
  const float* b_fx = (const float*)d_in[9];
  const float* W_fh = (const float*)d_in[10];
  const float* W_fc = (const float*)d_in[11];
  const float* W_tx = (const float*)d_in[12];
  const float* b_tx = (const float*)d_in[13];
  const float* W_tt = (const float*)d_in[14];
  const float* W_cx = (const float*)d_in[15];
  const float* b_cx = (const float*)d_in[16];
  const float* W_ch = (const float*)d_in[17];
  const float* W_ox = (const float*)d_in[18];
  const float* b_ox = (const float*)d_in[19];
  const float* W_oh = (const float*)d_in[20];
  const float* W_oc = (const float*)d_in[21];
  const float* W_ot = (const float*)d_in[22];

  unsigned short* Ap = (unsigned short*)d_ws;                                   // 44.04 MB
  unsigned short* Wp = (unsigned short*)((char*)d_ws + (size_t)B_SZ * KP * 2);  // +8.26 MB

  const long na4 = (long)B_SZ * KP / 4;
  prep_a_kernel<<<(int)((na4 + 255) / 256), 256, 0, stream>>>(x, h, c_prev, dl, Ap);
  const long nw4 = 6L * H_SZ * KP / 4;
  prep_w_kernel<<<(int)((nw4 + 255) / 256), 256, 0, stream>>>(
      W_ix, W_ih, W_ic, W_fx, W_fh, W_fc, W_tx, W_tt, W_cx, W_ch,
      W_ox, W_oh, W_oc, W_ot, Wp);

  lstm_main<<<512, 512, 0, stream>>>(Ap, Wp, c_prev, b_ix, b_fx, b_tx, b_cx, b_ox,
                                     (float*)d_out);
}